// Round 3
// baseline (2594.485 us; speedup 1.0000x reference)
//
#include <hip/hip_runtime.h>
#include <hip/hip_cooperative_groups.h>
#include <stdint.h>

namespace cg = cooperative_groups;

#define E 128
#define W 64
#define C 1024
#define S 8
#define NBUCK 4096

typedef unsigned long long u64;
typedef unsigned int u32;

__device__ __forceinline__ float sigm(float x) { return 1.0f / (1.0f + expf(-x)); }

struct SA { float xin[384]; float zp[256]; };
struct SB { float zl[512]; float hnewl[128]; float xl[384]; float zp[256]; };
struct SC { float hm[384]; float zp[256]; };
struct SD { float featl[256]; };
struct SE { float sc[C]; float red[256]; u64 keys[C]; u32 hist[NBUCK]; u64 coll[C]; int cnt; int thrB; };
struct SF { u64 keys[W * 64]; u32 hist[NBUCK]; u64 coll[W * 64]; int cnt; int thrB; };
union SMem { SA a; SB b; SC c; SD d; SE e; SF f; };

// ---------------------------------------------------------------------------
// One cooperative kernel per step. grid = 256 blocks x 256 threads.
// Phases: A lstm-z | B gates+mlp1 | C mlp2 | D scores | E softmax+rowtop | F topk
// ---------------------------------------------------------------------------
__global__ __launch_bounds__(256) void k_step(
    int step, int last,
    const float* __restrict__ ent_emb, const float* __restrict__ rel_emb,
    const float* __restrict__ relation,
    const float* __restrict__ W1, const float* __restrict__ b1,
    const float* __restrict__ W2, const float* __restrict__ b2,
    const float* __restrict__ lstm_k, const float* __restrict__ lstm_r,
    const float* __restrict__ lstm_b,
    const int* __restrict__ cand_rel_ids, const int* __restrict__ cand_ent_ids,
    const int* __restrict__ start_ent,
    float* __restrict__ out, float* __restrict__ ws)
{
  cg::grid_group grid = cg::this_grid();
  const int blk = blockIdx.x, tid = threadIdx.x;
  __shared__ SMem sm;

  // ---- ws layout (floats) ----
  float* Hst = ws;                       // [2][W][E]
  float* Cst = Hst + 2 * W * E;          // [2][W][E]
  float* zbuf = Cst + 2 * W * E;         // [W][512]
  float* hmidb = zbuf + W * 512;         // [W][384]
  float* featb = hmidb + W * 384;        // [W][256]
  float* scoresb = featb + W * 256;      // [W][C]
  u64* rowtop = (u64*)(scoresb + (size_t)W * C);   // [W][64]
  int* parent = (int*)(rowtop + W * 64);
  int* selb = parent + W;
  int* curid = selb + W;
  int* pridb = curid + W;
  int* peidb = pridb + W;

  float* Hn = Hst + (size_t)(step & 1) * W * E;
  float* Cn = Cst + (size_t)(step & 1) * W * E;
  const float* Hp = Hst + (size_t)((step + 1) & 1) * W * E;
  const float* Cp = Cst + (size_t)((step + 1) & 1) * W * E;

  // ================= phase A: lstm z = inp@K + h@R (step>0) =================
  if (step > 0) {
    const int w = blk >> 2, jr = blk & 3;
    const int jloc = tid & 127, slice = tid >> 7;
    const int j = jr * 128 + jloc;
    const int rid = pridb[w], eid = peidb[w], par = parent[w];
    for (int i = tid; i < 384; i += 256) {
      float v;
      if (i < 128) v = rel_emb[(size_t)rid * E + i];
      else if (i < 256) v = ent_emb[(size_t)eid * E + (i - 128)];
      else v = Hp[par * E + (i - 256)];
      sm.a.xin[i] = v;
    }
    __syncthreads();
    float a0 = 0.f, a1 = 0.f, a2 = 0.f, a3 = 0.f;
    if (slice == 0) {
      const float* Kp = lstm_k + j;
#pragma unroll 4
      for (int k = 0; k < 256; k += 4) {
        a0 += sm.a.xin[k]     * Kp[(size_t)(k)     * 512];
        a1 += sm.a.xin[k + 1] * Kp[(size_t)(k + 1) * 512];
        a2 += sm.a.xin[k + 2] * Kp[(size_t)(k + 2) * 512];
        a3 += sm.a.xin[k + 3] * Kp[(size_t)(k + 3) * 512];
      }
    } else {
      const float* Rp = lstm_r + j;
#pragma unroll 4
      for (int k = 0; k < 128; k += 4) {
        a0 += sm.a.xin[256 + k]     * Rp[(size_t)(k)     * 512];
        a1 += sm.a.xin[256 + k + 1] * Rp[(size_t)(k + 1) * 512];
        a2 += sm.a.xin[256 + k + 2] * Rp[(size_t)(k + 2) * 512];
        a3 += sm.a.xin[256 + k + 3] * Rp[(size_t)(k + 3) * 512];
      }
    }
    sm.a.zp[tid] = (a0 + a1) + (a2 + a3);
    __syncthreads();
    if (slice == 0)
      zbuf[(size_t)w * 512 + j] = lstm_b[j] + sm.a.zp[jloc] + sm.a.zp[128 + jloc];
  }
  __threadfence();
  grid.sync();

  // ================= phase B: gates + mlp1 ==================================
  if (blk < 192) {
    const int w = blk / 3, part = blk % 3;
    int cur;
    if (step == 0) {
      for (int i = tid; i < 128; i += 256) {
        sm.b.hnewl[i] = 0.f;
        if (part == 0) { Hn[w * E + i] = 0.f; Cn[w * E + i] = 0.f; }
      }
      cur = start_ent[w];
    } else {
      for (int i = tid; i < 512; i += 256) sm.b.zl[i] = zbuf[(size_t)w * 512 + i];
      __syncthreads();
      if (tid < 128) {
        const float zi = sm.b.zl[tid], zf = sm.b.zl[128 + tid],
                    zg = sm.b.zl[256 + tid], zo = sm.b.zl[384 + tid];
        const float cprev = Cp[parent[w] * E + tid];
        const float cn = sigm(zf) * cprev + sigm(zi) * tanhf(zg);
        const float hn = sigm(zo) * tanhf(cn);
        sm.b.hnewl[tid] = hn;
        if (part == 0) { Hn[w * E + tid] = hn; Cn[w * E + tid] = cn; }
      }
      cur = curid[w];
    }
    __syncthreads();
    for (int i = tid; i < 384; i += 256) {
      float v;
      if (i < 128) v = ent_emb[(size_t)cur * E + i];
      else if (i < 256) v = sm.b.hnewl[i - 128];
      else v = relation[i - 256];
      sm.b.xl[i] = v;
    }
    __syncthreads();
    const int jloc = tid & 127, slice = tid >> 7;
    const int j = part * 128 + jloc;
    const float* Wp = W1 + j;
    const int k0 = slice * 192;
    float a0 = 0.f, a1 = 0.f, a2 = 0.f, a3 = 0.f;
#pragma unroll 4
    for (int k = k0; k < k0 + 192; k += 4) {
      a0 += sm.b.xl[k]     * Wp[(size_t)(k)     * 384];
      a1 += sm.b.xl[k + 1] * Wp[(size_t)(k + 1) * 384];
      a2 += sm.b.xl[k + 2] * Wp[(size_t)(k + 2) * 384];
      a3 += sm.b.xl[k + 3] * Wp[(size_t)(k + 3) * 384];
    }
    sm.b.zp[tid] = (a0 + a1) + (a2 + a3);
    __syncthreads();
    if (slice == 0)
      hmidb[(size_t)w * 384 + j] =
          fmaxf(b1[j] + sm.b.zp[jloc] + sm.b.zp[128 + jloc], 0.f);
  }
  __threadfence();
  grid.sync();

  // ================= phase C: mlp2 -> feature ================================
  if (blk < 128) {
    const int w = blk >> 1, half = blk & 1;
    for (int i = tid; i < 384; i += 256) sm.c.hm[i] = hmidb[(size_t)w * 384 + i];
    __syncthreads();
    const int jloc = tid & 127, slice = tid >> 7;
    const int j = half * 128 + jloc;
    const float* Wp = W2 + j;
    const int k0 = slice * 192;
    float a0 = 0.f, a1 = 0.f, a2 = 0.f, a3 = 0.f;
#pragma unroll 4
    for (int k = k0; k < k0 + 192; k += 4) {
      a0 += sm.c.hm[k]     * Wp[(size_t)(k)     * 256];
      a1 += sm.c.hm[k + 1] * Wp[(size_t)(k + 1) * 256];
      a2 += sm.c.hm[k + 2] * Wp[(size_t)(k + 2) * 256];
      a3 += sm.c.hm[k + 3] * Wp[(size_t)(k + 3) * 256];
    }
    sm.c.zp[tid] = (a0 + a1) + (a2 + a3);
    __syncthreads();
    if (slice == 0)
      featb[(size_t)w * 256 + j] =
          fmaxf(b2[j] + sm.c.zp[jloc] + sm.c.zp[128 + jloc], 0.f);
  }
  __threadfence();
  grid.sync();

  // ================= phase D: candidate scoring ==============================
  {
    const int w = blk >> 2;
    const int c = ((blk & 3) << 8) + tid;
    sm.d.featl[tid] = featb[(size_t)w * 256 + tid];
    __syncthreads();
    const size_t base = (size_t)step * W * C + (size_t)w * C + c;
    const int rid = cand_rel_ids[base], eid = cand_ent_ids[base];
    const float4* rp = (const float4*)(rel_emb + (size_t)rid * E);
    const float4* ep = (const float4*)(ent_emb + (size_t)eid * E);
    const float4* f4 = (const float4*)sm.d.featl;
    float ax = 0.f, ay = 0.f, az = 0.f, aw = 0.f;
#pragma unroll
    for (int i = 0; i < 32; ++i) {
      const float4 r = rp[i], f = f4[i];
      ax += r.x * f.x; ay += r.y * f.y; az += r.z * f.z; aw += r.w * f.w;
    }
#pragma unroll
    for (int i = 0; i < 32; ++i) {
      const float4 e = ep[i], f = f4[32 + i];
      ax += e.x * f.x; ay += e.y * f.y; az += e.z * f.z; aw += e.w * f.w;
    }
    scoresb[(size_t)w * C + c] = (ax + ay) + (az + aw);
  }
  __threadfence();
  grid.sync();

  // ================= phase E: softmax + per-row top-64 =======================
  if (blk < 64) {
    const int w = blk;
    for (int i = tid; i < C; i += 256) sm.e.sc[i] = scoresb[(size_t)w * C + i];
    for (int i = tid; i < NBUCK; i += 256) sm.e.hist[i] = 0;
    if (tid == 0) sm.e.cnt = 0;
    __syncthreads();
    float m = -INFINITY;
    for (int i = tid; i < C; i += 256) m = fmaxf(m, sm.e.sc[i]);
    sm.e.red[tid] = m;
    __syncthreads();
    for (int s2 = 128; s2 > 0; s2 >>= 1) {
      if (tid < s2) sm.e.red[tid] = fmaxf(sm.e.red[tid], sm.e.red[tid + s2]);
      __syncthreads();
    }
    m = sm.e.red[0];
    __syncthreads();
    float sum = 0.f;
    for (int i = tid; i < C; i += 256) {
      const float p = expf(sm.e.sc[i] - m);
      sm.e.sc[i] = p;
      sum += p;
    }
    sm.e.red[tid] = sum;
    __syncthreads();
    for (int s2 = 128; s2 > 0; s2 >>= 1) {
      if (tid < s2) sm.e.red[tid] += sm.e.red[tid + s2];
      __syncthreads();
    }
    const float inv = 1.f / sm.e.red[0];
    __syncthreads();
    for (int i = tid; i < C; i += 256) {
      const float p = sm.e.sc[i] * inv;
      out[(size_t)step * W * C + (size_t)w * C + i] = p;
      if (!last) {
        const u32 mono = __float_as_uint(p) | 0x80000000u;
        const u64 key = ((u64)mono << 32) | (u32)~(u32)(w * C + i);
        sm.e.keys[i] = key;
        atomicAdd(&sm.e.hist[(mono >> 19) & 0xFFFu], 1u);
      }
    }
    if (!last) {
      __syncthreads();
      for (int off = 1; off < NBUCK; off <<= 1) {
        u32 tmp[NBUCK / 256];
        for (int i = tid, q = 0; i < NBUCK; i += 256, ++q)
          tmp[q] = (i + off < NBUCK) ? sm.e.hist[i + off] : 0u;
        __syncthreads();
        for (int i = tid, q = 0; i < NBUCK; i += 256, ++q) sm.e.hist[i] += tmp[q];
        __syncthreads();
      }
      for (int i = tid; i < NBUCK; i += 256) {
        const u32 here = sm.e.hist[i];
        const u32 nxt = (i + 1 < NBUCK) ? sm.e.hist[i + 1] : 0u;
        if (here >= 64u && nxt < 64u) sm.e.thrB = i;
      }
      __syncthreads();
      const int Bthr = sm.e.thrB;
      for (int i = tid; i < C; i += 256) {
        const u64 key = sm.e.keys[i];
        if ((int)((key >> 51) & 0xFFFull) >= Bthr) {
          const int q = atomicAdd(&sm.e.cnt, 1);
          sm.e.coll[q] = key;
        }
      }
      __syncthreads();
      const int M = sm.e.cnt;
      for (int i = tid; i < M; i += 256) {
        const u64 ki = sm.e.coll[i];
        int r = 0;
        for (int j2 = 0; j2 < M; ++j2) r += (sm.e.coll[j2] > ki);
        if (r < 64) rowtop[(size_t)w * 64 + r] = ki;
      }
    }
  }
  __threadfence();
  grid.sync();

  // ================= phase F: global top-64 + next-step ids ==================
  if (!last && blk == 0) {
    for (int i = tid; i < W * 64; i += 256) sm.f.keys[i] = rowtop[i];
    for (int i = tid; i < NBUCK; i += 256) sm.f.hist[i] = 0;
    if (tid == 0) sm.f.cnt = 0;
    __syncthreads();
    for (int i = tid; i < W * 64; i += 256)
      atomicAdd(&sm.f.hist[(u32)(sm.f.keys[i] >> 51) & 0xFFFu], 1u);
    __syncthreads();
    for (int off = 1; off < NBUCK; off <<= 1) {
      u32 tmp[NBUCK / 256];
      for (int i = tid, q = 0; i < NBUCK; i += 256, ++q)
        tmp[q] = (i + off < NBUCK) ? sm.f.hist[i + off] : 0u;
      __syncthreads();
      for (int i = tid, q = 0; i < NBUCK; i += 256, ++q) sm.f.hist[i] += tmp[q];
      __syncthreads();
    }
    for (int i = tid; i < NBUCK; i += 256) {
      const u32 here = sm.f.hist[i];
      const u32 nxt = (i + 1 < NBUCK) ? sm.f.hist[i + 1] : 0u;
      if (here >= 64u && nxt < 64u) sm.f.thrB = i;
    }
    __syncthreads();
    const int Bthr = sm.f.thrB;
    for (int i = tid; i < W * 64; i += 256) {
      const u64 key = sm.f.keys[i];
      if ((int)((key >> 51) & 0xFFFull) >= Bthr) {
        const int q = atomicAdd(&sm.f.cnt, 1);
        sm.f.coll[q] = key;
      }
    }
    __syncthreads();
    const int M = sm.f.cnt;
    for (int i = tid; i < M; i += 256) {
      const u64 ki = sm.f.coll[i];
      int r = 0;
      for (int j2 = 0; j2 < M; ++j2) r += (sm.f.coll[j2] > ki);
      if (r < 64) {
        const u32 flat = ~(u32)(ki & 0xFFFFFFFFull);
        const int p = (int)(flat >> 10);
        const int sl = (int)(flat & 1023u);
        parent[r] = p;
        selb[r] = sl;
        const size_t cbase = (size_t)step * W * C + (size_t)p * C + sl;
        const int rid = cand_rel_ids[cbase];
        const int eid = cand_ent_ids[cbase];
        pridb[r] = rid;
        peidb[r] = eid;
        curid[r] = eid;
      }
    }
  }
}

// ---------------------------------------------------------------------------
extern "C" void kernel_launch(void* const* d_in, const int* in_sizes, int n_in,
                              void* d_out, int out_size, void* d_ws, size_t ws_size,
                              hipStream_t stream) {
  const float* ent_emb  = (const float*)d_in[0];
  const float* rel_emb  = (const float*)d_in[1];
  const float* relation = (const float*)d_in[2];
  const float* W1 = (const float*)d_in[3];
  const float* b1 = (const float*)d_in[4];
  const float* W2 = (const float*)d_in[5];
  const float* b2 = (const float*)d_in[6];
  const float* lstm_k = (const float*)d_in[7];
  const float* lstm_r = (const float*)d_in[8];
  const float* lstm_b = (const float*)d_in[9];
  const int* cr = (const int*)d_in[10];
  const int* ce = (const int*)d_in[11];
  const int* start_ent = (const int*)d_in[12];
  float* out = (float*)d_out;
  float* ws = (float*)d_ws;

  for (int s = 0; s < S; ++s) {
    int step_v = s;
    int last_v = (s == S - 1) ? 1 : 0;
    void* args[] = { &step_v, &last_v, &ent_emb, &rel_emb, &relation,
                     &W1, &b1, &W2, &b2, &lstm_k, &lstm_r, &lstm_b,
                     &cr, &ce, &start_ent, &out, &ws };
    hipLaunchCooperativeKernel(reinterpret_cast<void*>(k_step),
                               dim3(256), dim3(256), args, 0, stream);
  }
}

// Round 4
// 800.437 us; speedup vs baseline: 3.2413x; 3.2413x over previous
//
#include <hip/hip_runtime.h>
#include <stdint.h>

#define E 128
#define W 64
#define C 1024
#define S 8
#define NBUCK 4096

typedef unsigned long long u64;
typedef unsigned int u32;

__device__ __forceinline__ float sigm(float x) { return 1.0f / (1.0f + expf(-x)); }

// ---------------------------------------------------------------------------
// kA: per-beam fused step. grid = 64 blocks x 1024 threads.
//   phase A: LSTM z = [rel_emb[rid], ent_emb[eid], h_parent] @ [K;R] + b, gates
//   phase B: x = [ent_emb[cur], h_new, relation];  hmid = relu(x@W1+b1)
//   phase C: feat = relu(hmid@W2+b2)
//   phase D: scores = dot(cand_emb, feat)  (1 candidate / thread)
//   phase E: softmax -> out
// ---------------------------------------------------------------------------
__global__ __launch_bounds__(1024) void kA(
    int step,
    const float* __restrict__ ent_emb, const float* __restrict__ rel_emb,
    const float* __restrict__ relation,
    const float* __restrict__ W1, const float* __restrict__ b1,
    const float* __restrict__ W2, const float* __restrict__ b2,
    const float* __restrict__ lstm_k, const float* __restrict__ lstm_r,
    const float* __restrict__ lstm_b,
    const int* __restrict__ cand_rel_ids, const int* __restrict__ cand_ent_ids,
    const int* __restrict__ start_ent,
    const int* __restrict__ parent, const int* __restrict__ prid,
    const int* __restrict__ peid, const int* __restrict__ curid,
    float* __restrict__ Hst, float* __restrict__ Cst,   // each 2*W*E
    float* __restrict__ out)
{
  const int w = blockIdx.x, tid = threadIdx.x;
  __shared__ __align__(16) float xin[384];
  __shared__ __align__(16) float zred[1024];
  __shared__ __align__(16) float z[512];
  __shared__ __align__(16) float hnew[128];
  __shared__ __align__(16) float xcat[384];
  __shared__ __align__(16) float hmid[384];
  __shared__ __align__(16) float feat[256];
  __shared__ float sred[32];

  float* Hn = Hst + (size_t)(step & 1) * W * E;
  float* Cn = Cst + (size_t)(step & 1) * W * E;
  const float* Hp = Hst + (size_t)((step + 1) & 1) * W * E;
  const float* Cp = Cst + (size_t)((step + 1) & 1) * W * E;

  // prefetch candidate ids for phase D (hides id-load latency under MLP)
  const size_t dbase = (size_t)step * W * C + (size_t)w * C + tid;
  const int d_rid = cand_rel_ids[dbase];
  const int d_eid = cand_ent_ids[dbase];

  int cur;
  // ---------------- phase A ------------------------------------------------
  if (step == 0) {
    if (tid < 128) {
      hnew[tid] = 0.f;
      Hn[w * E + tid] = 0.f;
      Cn[w * E + tid] = 0.f;
    }
    cur = start_ent[w];
  } else {
    const int par = parent[w];
    const int rid = prid[w], eid = peid[w];
    cur = curid[w];
    if (tid < 384) {
      float v;
      if (tid < 128) v = rel_emb[(size_t)rid * E + tid];
      else if (tid < 256) v = ent_emb[(size_t)eid * E + (tid - 128)];
      else v = Hp[par * E + (tid - 256)];
      xin[tid] = v;
    }
    __syncthreads();
    {
      const int j = tid & 511, half = tid >> 9;
      float a0 = 0.f, a1 = 0.f, a2 = 0.f, a3 = 0.f;
      if (half == 0) {
        const float* Kp = lstm_k + j;
#pragma unroll 4
        for (int k = 0; k < 192; k += 4) {
          a0 += xin[k]     * Kp[(size_t)(k)     * 512];
          a1 += xin[k + 1] * Kp[(size_t)(k + 1) * 512];
          a2 += xin[k + 2] * Kp[(size_t)(k + 2) * 512];
          a3 += xin[k + 3] * Kp[(size_t)(k + 3) * 512];
        }
      } else {
        const float* Kp = lstm_k + j;
#pragma unroll 4
        for (int k = 192; k < 256; k += 4) {
          a0 += xin[k]     * Kp[(size_t)(k)     * 512];
          a1 += xin[k + 1] * Kp[(size_t)(k + 1) * 512];
          a2 += xin[k + 2] * Kp[(size_t)(k + 2) * 512];
          a3 += xin[k + 3] * Kp[(size_t)(k + 3) * 512];
        }
        const float* Rp = lstm_r + j;
#pragma unroll 4
        for (int k = 0; k < 128; k += 4) {
          a0 += xin[256 + k]     * Rp[(size_t)(k)     * 512];
          a1 += xin[256 + k + 1] * Rp[(size_t)(k + 1) * 512];
          a2 += xin[256 + k + 2] * Rp[(size_t)(k + 2) * 512];
          a3 += xin[256 + k + 3] * Rp[(size_t)(k + 3) * 512];
        }
      }
      zred[tid] = (a0 + a1) + (a2 + a3);
    }
    __syncthreads();
    if (tid < 512) z[tid] = lstm_b[tid] + zred[tid] + zred[512 + tid];
    __syncthreads();
    if (tid < 128) {
      const float zi = z[tid], zf = z[128 + tid], zg = z[256 + tid], zo = z[384 + tid];
      const float cn = sigm(zf) * Cp[par * E + tid] + sigm(zi) * tanhf(zg);
      const float hn = sigm(zo) * tanhf(cn);
      hnew[tid] = hn;
      Hn[w * E + tid] = hn;
      Cn[w * E + tid] = cn;
    }
  }
  __syncthreads();

  // ---------------- phase B: xcat + MLP1 -----------------------------------
  if (tid < 384) {
    float v;
    if (tid < 128) v = ent_emb[(size_t)cur * E + tid];
    else if (tid < 256) v = hnew[tid - 128];
    else v = relation[tid - 256];
    xcat[tid] = v;
  }
  __syncthreads();
  if (tid < 768) {
    const int sl = (tid >= 384) ? 1 : 0;
    const int j = tid - sl * 384;
    const int k0 = sl * 192;
    const float* Wp = W1 + j;
    float a0 = 0.f, a1 = 0.f, a2 = 0.f, a3 = 0.f;
#pragma unroll 4
    for (int k = k0; k < k0 + 192; k += 4) {
      a0 += xcat[k]     * Wp[(size_t)(k)     * 384];
      a1 += xcat[k + 1] * Wp[(size_t)(k + 1) * 384];
      a2 += xcat[k + 2] * Wp[(size_t)(k + 2) * 384];
      a3 += xcat[k + 3] * Wp[(size_t)(k + 3) * 384];
    }
    zred[tid] = (a0 + a1) + (a2 + a3);
  }
  __syncthreads();
  if (tid < 384) hmid[tid] = fmaxf(b1[tid] + zred[tid] + zred[384 + tid], 0.f);
  __syncthreads();

  // ---------------- phase C: MLP2 ------------------------------------------
  {
    const int j = tid & 255, sl = tid >> 8;
    const int k0 = sl * 96;
    const float* Wp = W2 + j;
    float a0 = 0.f, a1 = 0.f, a2 = 0.f, a3 = 0.f;
#pragma unroll 4
    for (int k = k0; k < k0 + 96; k += 4) {
      a0 += hmid[k]     * Wp[(size_t)(k)     * 256];
      a1 += hmid[k + 1] * Wp[(size_t)(k + 1) * 256];
      a2 += hmid[k + 2] * Wp[(size_t)(k + 2) * 256];
      a3 += hmid[k + 3] * Wp[(size_t)(k + 3) * 256];
    }
    zred[tid] = (a0 + a1) + (a2 + a3);
  }
  __syncthreads();
  if (tid < 256)
    feat[tid] = fmaxf(b2[tid] + zred[tid] + zred[256 + tid] + zred[512 + tid] + zred[768 + tid], 0.f);
  __syncthreads();

  // ---------------- phase D: scoring (1 cand / thread) ---------------------
  float score;
  {
    const float4* rp = (const float4*)(rel_emb + (size_t)d_rid * E);
    const float4* ep = (const float4*)(ent_emb + (size_t)d_eid * E);
    const float4* f4 = (const float4*)feat;
    float ax = 0.f, ay = 0.f, az = 0.f, aw = 0.f;
#pragma unroll
    for (int i = 0; i < 32; ++i) {
      const float4 r = rp[i], f = f4[i];
      ax += r.x * f.x; ay += r.y * f.y; az += r.z * f.z; aw += r.w * f.w;
    }
#pragma unroll
    for (int i = 0; i < 32; ++i) {
      const float4 e = ep[i], f = f4[32 + i];
      ax += e.x * f.x; ay += e.y * f.y; az += e.z * f.z; aw += e.w * f.w;
    }
    score = (ax + ay) + (az + aw);
  }

  // ---------------- phase E: softmax ---------------------------------------
  float v = score;
#pragma unroll
  for (int m = 32; m; m >>= 1) v = fmaxf(v, __shfl_xor(v, m, 64));
  if ((tid & 63) == 0) sred[tid >> 6] = v;
  __syncthreads();
  if (tid == 0) {
    float mm = sred[0];
#pragma unroll
    for (int i = 1; i < 16; ++i) mm = fmaxf(mm, sred[i]);
    sred[16] = mm;
  }
  __syncthreads();
  const float m = sred[16];
  const float pexp = expf(score - m);
  v = pexp;
#pragma unroll
  for (int mm = 32; mm; mm >>= 1) v += __shfl_xor(v, mm, 64);
  if ((tid & 63) == 0) sred[tid >> 6] = v;
  __syncthreads();
  if (tid == 0) {
    float ss = sred[0];
#pragma unroll
    for (int i = 1; i < 16; ++i) ss += sred[i];
    sred[17] = 1.f / ss;
  }
  __syncthreads();
  out[(size_t)step * W * C + (size_t)w * C + tid] = pexp * sred[17];
}

// ---------------------------------------------------------------------------
// kB: global top-64 over out[step] (65536 probs), write parent/sel + gathered
//     ids for next step. grid = 1 x 1024.
// ---------------------------------------------------------------------------
__global__ __launch_bounds__(1024) void kB(
    int step, const float* __restrict__ out,
    const int* __restrict__ cand_rel_ids, const int* __restrict__ cand_ent_ids,
    int* __restrict__ parent, int* __restrict__ selb,
    int* __restrict__ prid, int* __restrict__ peid, int* __restrict__ curid)
{
  const int tid = threadIdx.x;
  __shared__ u32 hist[NBUCK];
  __shared__ u64 coll[1024];
  __shared__ int s_cnt, s_B;
  const float* probs = out + (size_t)step * W * C;

  for (int i = tid; i < NBUCK; i += 1024) hist[i] = 0;
  if (tid == 0) s_cnt = 0;
  __syncthreads();
  for (int i = tid; i < W * C; i += 1024) {
    const u32 mono = __float_as_uint(probs[i]) | 0x80000000u;
    atomicAdd(&hist[(mono >> 19) & 0xFFFu], 1u);
  }
  __syncthreads();
  // suffix scan
  for (int off = 1; off < NBUCK; off <<= 1) {
    u32 tmp[NBUCK / 1024];
    for (int i = tid, q = 0; i < NBUCK; i += 1024, ++q)
      tmp[q] = (i + off < NBUCK) ? hist[i + off] : 0u;
    __syncthreads();
    for (int i = tid, q = 0; i < NBUCK; i += 1024, ++q) hist[i] += tmp[q];
    __syncthreads();
  }
  for (int i = tid; i < NBUCK; i += 1024) {
    const u32 here = hist[i];
    const u32 nxt = (i + 1 < NBUCK) ? hist[i + 1] : 0u;
    if (here >= 64u && nxt < 64u) s_B = i;
  }
  __syncthreads();
  const int Bthr = s_B;
  for (int i = tid; i < W * C; i += 1024) {
    const u32 mono = __float_as_uint(probs[i]) | 0x80000000u;
    if ((int)((mono >> 19) & 0xFFFu) >= Bthr) {
      const int q = atomicAdd(&s_cnt, 1);
      if (q < 1024) coll[q] = ((u64)mono << 32) | (u32)~(u32)i;
    }
  }
  __syncthreads();
  const int M = min(s_cnt, 1024);
  for (int i = tid; i < M; i += 1024) {
    const u64 ki = coll[i];
    int r = 0;
    for (int j = 0; j < M; ++j) r += (coll[j] > ki);
    if (r < 64) {
      const u32 flat = ~(u32)(ki & 0xFFFFFFFFull);
      const int p = (int)(flat >> 10);
      const int sl = (int)(flat & 1023u);
      parent[r] = p;
      selb[r] = sl;
      const size_t cbase = (size_t)step * W * C + (size_t)p * C + sl;
      const int rid = cand_rel_ids[cbase];
      const int eid = cand_ent_ids[cbase];
      prid[r] = rid;
      peid[r] = eid;
      curid[r] = eid;
    }
  }
}

// ---------------------------------------------------------------------------
extern "C" void kernel_launch(void* const* d_in, const int* in_sizes, int n_in,
                              void* d_out, int out_size, void* d_ws, size_t ws_size,
                              hipStream_t stream) {
  const float* ent_emb  = (const float*)d_in[0];
  const float* rel_emb  = (const float*)d_in[1];
  const float* relation = (const float*)d_in[2];
  const float* W1 = (const float*)d_in[3];
  const float* b1 = (const float*)d_in[4];
  const float* W2 = (const float*)d_in[5];
  const float* b2 = (const float*)d_in[6];
  const float* lstm_k = (const float*)d_in[7];
  const float* lstm_r = (const float*)d_in[8];
  const float* lstm_b = (const float*)d_in[9];
  const int* cr = (const int*)d_in[10];
  const int* ce = (const int*)d_in[11];
  const int* start_ent = (const int*)d_in[12];
  float* out = (float*)d_out;

  float* Hst = (float*)d_ws;                       // 2*W*E
  float* Cst = Hst + (size_t)2 * W * E;            // 2*W*E
  int* parent = (int*)(Cst + (size_t)2 * W * E);
  int* selb   = parent + W;
  int* prid   = selb + W;
  int* peid   = prid + W;
  int* curid  = peid + W;

  for (int s = 0; s < S; ++s) {
    kA<<<W, 1024, 0, stream>>>(s, ent_emb, rel_emb, relation, W1, b1, W2, b2,
                               lstm_k, lstm_r, lstm_b, cr, ce, start_ent,
                               parent, prid, peid, curid, Hst, Cst, out);
    if (s < S - 1)
      kB<<<1, 1024, 0, stream>>>(s, out, cr, ce, parent, selb, prid, peid, curid);
  }
}

// Round 5
// 615.949 us; speedup vs baseline: 4.2122x; 1.2995x over previous
//
#include <hip/hip_runtime.h>
#include <stdint.h>

#define E 128
#define W 64
#define C 1024
#define S 8
#define NBUCK 4096

typedef unsigned long long u64;
typedef unsigned int u32;

__device__ __forceinline__ float sigm(float x) { return 1.0f / (1.0f + expf(-x)); }

// ---------------------------------------------------------------------------
// kFeat: per-beam LSTM + MLP chain (weight-bound). grid = 64 x 1024.
//   A: z = [rel_emb[rid], ent_emb[eid], h_par] @ [K;R] + b -> gates -> h,c
//   B: hmid = relu([ent_emb[cur], h, relation] @ W1 + b1)
//   C: feat = relu(hmid @ W2 + b2) -> featb[w][256]
// ---------------------------------------------------------------------------
__global__ __launch_bounds__(1024) void kFeat(
    int step,
    const float* __restrict__ ent_emb, const float* __restrict__ rel_emb,
    const float* __restrict__ relation,
    const float* __restrict__ W1, const float* __restrict__ b1,
    const float* __restrict__ W2, const float* __restrict__ b2,
    const float* __restrict__ lstm_k, const float* __restrict__ lstm_r,
    const float* __restrict__ lstm_b,
    const int* __restrict__ start_ent,
    const int* __restrict__ parent, const int* __restrict__ prid,
    const int* __restrict__ peid, const int* __restrict__ curid,
    float* __restrict__ Hst, float* __restrict__ Cst,   // each 2*W*E
    float* __restrict__ featb)                           // W*256
{
  const int w = blockIdx.x, tid = threadIdx.x;
  __shared__ __align__(16) float xin[384];
  __shared__ __align__(16) float zred[1024];
  __shared__ __align__(16) float z[512];
  __shared__ __align__(16) float hnew[128];
  __shared__ __align__(16) float xcat[384];
  __shared__ __align__(16) float hmid[384];

  float* Hn = Hst + (size_t)(step & 1) * W * E;
  float* Cn = Cst + (size_t)(step & 1) * W * E;
  const float* Hp = Hst + (size_t)((step + 1) & 1) * W * E;
  const float* Cp = Cst + (size_t)((step + 1) & 1) * W * E;

  int cur;
  // ---------------- phase A ------------------------------------------------
  if (step == 0) {
    if (tid < 128) {
      hnew[tid] = 0.f;
      Hn[w * E + tid] = 0.f;
      Cn[w * E + tid] = 0.f;
    }
    cur = start_ent[w];
  } else {
    const int par = parent[w];
    const int rid = prid[w], eid = peid[w];
    cur = curid[w];
    if (tid < 384) {
      float v;
      if (tid < 128) v = rel_emb[(size_t)rid * E + tid];
      else if (tid < 256) v = ent_emb[(size_t)eid * E + (tid - 128)];
      else v = Hp[par * E + (tid - 256)];
      xin[tid] = v;
    }
    __syncthreads();
    {
      const int j = tid & 511, half = tid >> 9;
      float a0 = 0.f, a1 = 0.f, a2 = 0.f, a3 = 0.f;
      if (half == 0) {
        const float* Kp = lstm_k + j;
#pragma unroll 4
        for (int k = 0; k < 192; k += 4) {
          a0 += xin[k]     * Kp[(size_t)(k)     * 512];
          a1 += xin[k + 1] * Kp[(size_t)(k + 1) * 512];
          a2 += xin[k + 2] * Kp[(size_t)(k + 2) * 512];
          a3 += xin[k + 3] * Kp[(size_t)(k + 3) * 512];
        }
      } else {
        const float* Kp = lstm_k + j;
#pragma unroll 4
        for (int k = 192; k < 256; k += 4) {
          a0 += xin[k]     * Kp[(size_t)(k)     * 512];
          a1 += xin[k + 1] * Kp[(size_t)(k + 1) * 512];
          a2 += xin[k + 2] * Kp[(size_t)(k + 2) * 512];
          a3 += xin[k + 3] * Kp[(size_t)(k + 3) * 512];
        }
        const float* Rp = lstm_r + j;
#pragma unroll 4
        for (int k = 0; k < 128; k += 4) {
          a0 += xin[256 + k]     * Rp[(size_t)(k)     * 512];
          a1 += xin[256 + k + 1] * Rp[(size_t)(k + 1) * 512];
          a2 += xin[256 + k + 2] * Rp[(size_t)(k + 2) * 512];
          a3 += xin[256 + k + 3] * Rp[(size_t)(k + 3) * 512];
        }
      }
      zred[tid] = (a0 + a1) + (a2 + a3);
    }
    __syncthreads();
    if (tid < 512) z[tid] = lstm_b[tid] + zred[tid] + zred[512 + tid];
    __syncthreads();
    if (tid < 128) {
      const float zi = z[tid], zf = z[128 + tid], zg = z[256 + tid], zo = z[384 + tid];
      const float cn = sigm(zf) * Cp[par * E + tid] + sigm(zi) * tanhf(zg);
      const float hn = sigm(zo) * tanhf(cn);
      hnew[tid] = hn;
      Hn[w * E + tid] = hn;
      Cn[w * E + tid] = cn;
    }
  }
  __syncthreads();

  // ---------------- phase B: xcat + MLP1 -----------------------------------
  if (tid < 384) {
    float v;
    if (tid < 128) v = ent_emb[(size_t)cur * E + tid];
    else if (tid < 256) v = hnew[tid - 128];
    else v = relation[tid - 256];
    xcat[tid] = v;
  }
  __syncthreads();
  if (tid < 768) {
    const int sl = (tid >= 384) ? 1 : 0;
    const int j = tid - sl * 384;
    const int k0 = sl * 192;
    const float* Wp = W1 + j;
    float a0 = 0.f, a1 = 0.f, a2 = 0.f, a3 = 0.f;
#pragma unroll 4
    for (int k = k0; k < k0 + 192; k += 4) {
      a0 += xcat[k]     * Wp[(size_t)(k)     * 384];
      a1 += xcat[k + 1] * Wp[(size_t)(k + 1) * 384];
      a2 += xcat[k + 2] * Wp[(size_t)(k + 2) * 384];
      a3 += xcat[k + 3] * Wp[(size_t)(k + 3) * 384];
    }
    zred[tid] = (a0 + a1) + (a2 + a3);
  }
  __syncthreads();
  if (tid < 384) hmid[tid] = fmaxf(b1[tid] + zred[tid] + zred[384 + tid], 0.f);
  __syncthreads();

  // ---------------- phase C: MLP2 ------------------------------------------
  {
    const int j = tid & 255, sl = tid >> 8;
    const int k0 = sl * 96;
    const float* Wp = W2 + j;
    float a0 = 0.f, a1 = 0.f, a2 = 0.f, a3 = 0.f;
#pragma unroll 4
    for (int k = k0; k < k0 + 96; k += 4) {
      a0 += hmid[k]     * Wp[(size_t)(k)     * 256];
      a1 += hmid[k + 1] * Wp[(size_t)(k + 1) * 256];
      a2 += hmid[k + 2] * Wp[(size_t)(k + 2) * 256];
      a3 += hmid[k + 3] * Wp[(size_t)(k + 3) * 256];
    }
    zred[tid] = (a0 + a1) + (a2 + a3);
  }
  __syncthreads();
  if (tid < 256)
    featb[(size_t)w * 256 + tid] =
        fmaxf(b2[tid] + zred[tid] + zred[256 + tid] + zred[512 + tid] + zred[768 + tid], 0.f);
}

// ---------------------------------------------------------------------------
// kScore: gather-bound scoring, 4 threads/candidate. grid = 512 x 512.
//   block b: beam w = b>>3, candidates c0 = (b&7)*128 .. +128
// ---------------------------------------------------------------------------
__global__ __launch_bounds__(512) void kScore(
    int step,
    const float* __restrict__ ent_emb, const float* __restrict__ rel_emb,
    const int* __restrict__ cand_rel_ids, const int* __restrict__ cand_ent_ids,
    const float* __restrict__ featb, float* __restrict__ scoresb)
{
  const int b = blockIdx.x, tid = threadIdx.x;
  const int w = b >> 3, c0 = (b & 7) << 7;
  __shared__ __align__(16) float featl[256];
  __shared__ int srid[128], seid[128];

  const size_t idbase = (size_t)step * W * C + (size_t)w * C + c0;
  if (tid < 256) featl[tid] = featb[(size_t)w * 256 + tid];
  else if (tid < 384) srid[tid - 256] = cand_rel_ids[idbase + (tid - 256)];
  else seid[tid - 384] = cand_ent_ids[idbase + (tid - 384)];
  __syncthreads();

  const int cl = tid >> 2, j = tid & 3;
  const float4* rp = (const float4*)(rel_emb + (size_t)srid[cl] * E);
  const float4* ep = (const float4*)(ent_emb + (size_t)seid[cl] * E);
  const float4* f4 = (const float4*)featl;
  float ax = 0.f, ay = 0.f, az = 0.f, aw = 0.f;
#pragma unroll
  for (int i = 0; i < 8; ++i) {
    const float4 r = rp[j + 4 * i], f = f4[j + 4 * i];
    ax += r.x * f.x; ay += r.y * f.y; az += r.z * f.z; aw += r.w * f.w;
  }
#pragma unroll
  for (int i = 0; i < 8; ++i) {
    const float4 e = ep[j + 4 * i], f = f4[32 + j + 4 * i];
    ax += e.x * f.x; ay += e.y * f.y; az += e.z * f.z; aw += e.w * f.w;
  }
  float acc = (ax + ay) + (az + aw);
  acc += __shfl_xor(acc, 1, 64);
  acc += __shfl_xor(acc, 2, 64);
  if (j == 0) scoresb[(size_t)w * C + c0 + cl] = acc;
}

// ---------------------------------------------------------------------------
// kProb: softmax + probs write + per-row top-64. grid = 64 x 1024.
// ---------------------------------------------------------------------------
__global__ __launch_bounds__(1024) void kProb(
    int step, int last, const float* __restrict__ scoresb,
    float* __restrict__ out, u64* __restrict__ rowtop)
{
  const int w = blockIdx.x, tid = threadIdx.x;
  __shared__ float sred[32];
  __shared__ u32 hist[NBUCK];
  __shared__ u64 coll[C];
  __shared__ int s_cnt, s_B;

  const float score = scoresb[(size_t)w * C + tid];

  float v = score;
#pragma unroll
  for (int m = 32; m; m >>= 1) v = fmaxf(v, __shfl_xor(v, m, 64));
  if ((tid & 63) == 0) sred[tid >> 6] = v;
  __syncthreads();
  if (tid == 0) {
    float mm = sred[0];
#pragma unroll
    for (int i = 1; i < 16; ++i) mm = fmaxf(mm, sred[i]);
    sred[16] = mm;
  }
  __syncthreads();
  const float m = sred[16];
  const float pexp = expf(score - m);
  v = pexp;
#pragma unroll
  for (int mm2 = 32; mm2; mm2 >>= 1) v += __shfl_xor(v, mm2, 64);
  if ((tid & 63) == 0) sred[tid >> 6] = v;
  __syncthreads();
  if (tid == 0) {
    float ss = sred[0];
#pragma unroll
    for (int i = 1; i < 16; ++i) ss += sred[i];
    sred[17] = 1.f / ss;
  }
  __syncthreads();
  const float prob = pexp * sred[17];
  out[(size_t)step * W * C + (size_t)w * C + tid] = prob;
  if (last) return;

  for (int i = tid; i < NBUCK; i += 1024) hist[i] = 0;
  if (tid == 0) s_cnt = 0;
  __syncthreads();
  const u32 mono = __float_as_uint(prob) | 0x80000000u;
  const u64 key = ((u64)mono << 32) | (u32)~(u32)(w * C + tid);
  atomicAdd(&hist[(mono >> 19) & 0xFFFu], 1u);
  __syncthreads();
  // suffix scan
  for (int off = 1; off < NBUCK; off <<= 1) {
    u32 tmp[NBUCK / 1024];
    for (int i = tid, q = 0; i < NBUCK; i += 1024, ++q)
      tmp[q] = (i + off < NBUCK) ? hist[i + off] : 0u;
    __syncthreads();
    for (int i = tid, q = 0; i < NBUCK; i += 1024, ++q) hist[i] += tmp[q];
    __syncthreads();
  }
  for (int i = tid; i < NBUCK; i += 1024) {
    const u32 here = hist[i];
    const u32 nxt = (i + 1 < NBUCK) ? hist[i + 1] : 0u;
    if (here >= 64u && nxt < 64u) s_B = i;
  }
  __syncthreads();
  if ((int)((mono >> 19) & 0xFFFu) >= s_B) {
    const int q = atomicAdd(&s_cnt, 1);
    coll[q] = key;
  }
  __syncthreads();
  const int M = s_cnt;
  for (int i = tid; i < M; i += 1024) {
    const u64 ki = coll[i];
    int r = 0;
    for (int j = 0; j < M; ++j) r += (coll[j] > ki);
    if (r < 64) rowtop[(size_t)w * 64 + r] = ki;
  }
}

// ---------------------------------------------------------------------------
// kTop: global top-64 over 64*64 row winners + id gather. grid = 1 x 256.
// ---------------------------------------------------------------------------
__global__ __launch_bounds__(256) void kTop(
    int step, const u64* __restrict__ rowtop,
    const int* __restrict__ cand_rel_ids, const int* __restrict__ cand_ent_ids,
    int* __restrict__ parent, int* __restrict__ prid,
    int* __restrict__ peid, int* __restrict__ curid)
{
  const int tid = threadIdx.x;
  __shared__ u64 keys[W * 64];
  __shared__ u32 hist[NBUCK];
  __shared__ u64 coll[W * 64];
  __shared__ int s_cnt, s_B;

  for (int i = tid; i < W * 64; i += 256) keys[i] = rowtop[i];
  for (int i = tid; i < NBUCK; i += 256) hist[i] = 0;
  if (tid == 0) s_cnt = 0;
  __syncthreads();
  for (int i = tid; i < W * 64; i += 256)
    atomicAdd(&hist[(u32)(keys[i] >> 51) & 0xFFFu], 1u);
  __syncthreads();
  for (int off = 1; off < NBUCK; off <<= 1) {
    u32 tmp[NBUCK / 256];
    for (int i = tid, q = 0; i < NBUCK; i += 256, ++q)
      tmp[q] = (i + off < NBUCK) ? hist[i + off] : 0u;
    __syncthreads();
    for (int i = tid, q = 0; i < NBUCK; i += 256, ++q) hist[i] += tmp[q];
    __syncthreads();
  }
  for (int i = tid; i < NBUCK; i += 256) {
    const u32 here = hist[i];
    const u32 nxt = (i + 1 < NBUCK) ? hist[i + 1] : 0u;
    if (here >= 64u && nxt < 64u) s_B = i;
  }
  __syncthreads();
  const int Bthr = s_B;
  for (int i = tid; i < W * 64; i += 256) {
    const u64 key = keys[i];
    if ((int)((key >> 51) & 0xFFFull) >= Bthr) {
      const int q = atomicAdd(&s_cnt, 1);
      coll[q] = key;
    }
  }
  __syncthreads();
  const int M = s_cnt;
  for (int i = tid; i < M; i += 256) {
    const u64 ki = coll[i];
    int r = 0;
    for (int j = 0; j < M; ++j) r += (coll[j] > ki);
    if (r < 64) {
      const u32 flat = ~(u32)(ki & 0xFFFFFFFFull);
      const int p = (int)(flat >> 10);
      const int sl = (int)(flat & 1023u);
      parent[r] = p;
      const size_t cbase = (size_t)step * W * C + (size_t)p * C + sl;
      const int rid = cand_rel_ids[cbase];
      const int eid = cand_ent_ids[cbase];
      prid[r] = rid;
      peid[r] = eid;
      curid[r] = eid;
    }
  }
}

// ---------------------------------------------------------------------------
extern "C" void kernel_launch(void* const* d_in, const int* in_sizes, int n_in,
                              void* d_out, int out_size, void* d_ws, size_t ws_size,
                              hipStream_t stream) {
  const float* ent_emb  = (const float*)d_in[0];
  const float* rel_emb  = (const float*)d_in[1];
  const float* relation = (const float*)d_in[2];
  const float* W1 = (const float*)d_in[3];
  const float* b1 = (const float*)d_in[4];
  const float* W2 = (const float*)d_in[5];
  const float* b2 = (const float*)d_in[6];
  const float* lstm_k = (const float*)d_in[7];
  const float* lstm_r = (const float*)d_in[8];
  const float* lstm_b = (const float*)d_in[9];
  const int* cr = (const int*)d_in[10];
  const int* ce = (const int*)d_in[11];
  const int* start_ent = (const int*)d_in[12];
  float* out = (float*)d_out;

  float* Hst = (float*)d_ws;                                // 2*W*E
  float* Cst = Hst + (size_t)2 * W * E;                     // 2*W*E
  float* featb = Cst + (size_t)2 * W * E;                   // W*256
  float* scoresb = featb + (size_t)W * 256;                 // W*C
  u64* rowtop = (u64*)(scoresb + (size_t)W * C);            // W*64 (8B aligned)
  int* parent = (int*)(rowtop + (size_t)W * 64);
  int* prid   = parent + W;
  int* peid   = prid + W;
  int* curid  = peid + W;

  for (int s = 0; s < S; ++s) {
    kFeat<<<W, 1024, 0, stream>>>(s, ent_emb, rel_emb, relation, W1, b1, W2, b2,
                                  lstm_k, lstm_r, lstm_b, start_ent,
                                  parent, prid, peid, curid, Hst, Cst, featb);
    kScore<<<512, 512, 0, stream>>>(s, ent_emb, rel_emb, cr, ce, featb, scoresb);
    kProb<<<W, 1024, 0, stream>>>(s, (s == S - 1) ? 1 : 0, scoresb, out, rowtop);
    if (s < S - 1)
      kTop<<<1, 256, 0, stream>>>(s, rowtop, cr, ce, parent, prid, peid, curid);
  }
}